// Round 1
// baseline (487.552 us; speedup 1.0000x reference)
//
#include <hip/hip_runtime.h>
#include <stdint.h>
#include <stddef.h>

#define SEQ 2048
#define NH 16
#define DH 64
#define DM 1024
#define NROWS 8192  // B*T

typedef __attribute__((ext_vector_type(4))) float f32x4;
typedef __attribute__((ext_vector_type(8))) short s16x8;

__device__ __forceinline__ unsigned short f2bf(float f) {
  unsigned int u = __builtin_bit_cast(unsigned int, f);
  u += 0x7fffu + ((u >> 16) & 1u);
  return (unsigned short)(u >> 16);
}

__device__ __forceinline__ void async16(const void* g, void* l) {
  __builtin_amdgcn_global_load_lds(
      (const __attribute__((address_space(1))) unsigned int*)g,
      (__attribute__((address_space(3))) unsigned int*)l, 16, 0, 0);
}

// ---------------- fp32 -> bf16 cast (8 elems/thread) ----------------
__global__ __launch_bounds__(256) void cast_bf16_kernel(const float* __restrict__ src,
                                                        short* __restrict__ dst, int n8) {
  int i = blockIdx.x * 256 + threadIdx.x;
  if (i >= n8) return;
  const float4* s4 = (const float4*)src;
  float4 a = s4[2 * i], b = s4[2 * i + 1];
  s16x8 o;
  o[0] = (short)f2bf(a.x); o[1] = (short)f2bf(a.y);
  o[2] = (short)f2bf(a.z); o[3] = (short)f2bf(a.w);
  o[4] = (short)f2bf(b.x); o[5] = (short)f2bf(b.y);
  o[6] = (short)f2bf(b.z); o[7] = (short)f2bf(b.w);
  *(s16x8*)(dst + (size_t)8 * i) = o;
}

// ---------------- NT GEMM: C[m][n] = sum_k A[m][k] * B[n][k] ----------------
// MODE 0: C bf16 row-major [M,N]
// MODE 1: C bf16 scatter   [B,NH,SEQ,DH]   (Q/K layout)
// MODE 2: C fp32 row-major [M,N]           (final output)
// MODE 3: C bf16 scatter   [B,NH,DH,SEQ]   (V transposed layout)
template <int MODE>
__global__ __launch_bounds__(256) void gemm_nt(const short* __restrict__ A,
                                               const short* __restrict__ B,
                                               void* __restrict__ C,
                                               int M, int N, int K) {
  __shared__ __align__(16) short As[128 * 32];
  __shared__ __align__(16) short Bs[128 * 32];
  const int tid = threadIdx.x;
  const int lane = tid & 63, wave = tid >> 6;
  const int l15 = lane & 15, quad = lane >> 4;
  const int lk8 = quad * 8;
  const int bm = blockIdx.y * 128, bn = blockIdx.x * 128;
  const int wm = (wave >> 1) * 64, wn = (wave & 1) * 64;

  const short* Ab = A + (size_t)bm * K;
  const short* Bb = B + (size_t)bn * K;

  f32x4 acc[4][4];
#pragma unroll
  for (int i = 0; i < 4; i++)
#pragma unroll
    for (int j = 0; j < 4; j++) acc[i][j] = (f32x4)0.f;

  const int srow = tid >> 2;        // 0..63
  const int scol = (tid & 3) * 8;   // 0,8,16,24

  for (int k0 = 0; k0 < K; k0 += 32) {
#pragma unroll
    for (int i = 0; i < 2; i++) {
      int row = i * 64 + srow;
      async16(Ab + (size_t)row * K + k0 + scol, As + ((size_t)(i * 256 + tid)) * 8);
      async16(Bb + (size_t)row * K + k0 + scol, Bs + ((size_t)(i * 256 + tid)) * 8);
    }
    __syncthreads();
    s16x8 af[4], bf[4];
#pragma unroll
    for (int t = 0; t < 4; t++) af[t] = *(const s16x8*)(As + (wm + t * 16 + l15) * 32 + lk8);
#pragma unroll
    for (int t = 0; t < 4; t++) bf[t] = *(const s16x8*)(Bs + (wn + t * 16 + l15) * 32 + lk8);
#pragma unroll
    for (int mt = 0; mt < 4; mt++)
#pragma unroll
      for (int nt = 0; nt < 4; nt++)
        acc[mt][nt] = __builtin_amdgcn_mfma_f32_16x16x32_bf16(af[mt], bf[nt], acc[mt][nt], 0, 0, 0);
    __syncthreads();
  }

#pragma unroll
  for (int mt = 0; mt < 4; mt++) {
#pragma unroll
    for (int r = 0; r < 4; r++) {
      int m = bm + wm + mt * 16 + quad * 4 + r;
#pragma unroll
      for (int nt = 0; nt < 4; nt++) {
        int n = bn + wn + nt * 16 + l15;
        float v = acc[mt][nt][r];
        if constexpr (MODE == 2) {
          ((float*)C)[(size_t)m * N + n] = v;
        } else if constexpr (MODE == 0) {
          ((short*)C)[(size_t)m * N + n] = (short)f2bf(v);
        } else if constexpr (MODE == 1) {
          int b = m >> 11, t = m & (SEQ - 1);
          int h = n >> 6, d = n & 63;
          ((short*)C)[((((size_t)b * NH + h) * SEQ + t) << 6) + d] = (short)f2bf(v);
        } else {  // MODE 3: V transposed [B,NH,DH,SEQ]
          int b = m >> 11, t = m & (SEQ - 1);
          int h = n >> 6, d = n & 63;
          ((short*)C)[(((size_t)b * NH + h) * DH + d) * SEQ + t] = (short)f2bf(v);
        }
      }
    }
  }
}

// ---------------- causal flash attention ----------------
// Q,K: [B,NH,SEQ,DH] bf16; V: [B,NH,DH,SEQ] bf16 (transposed); O: [B,SEQ,DM] bf16
__global__ __launch_bounds__(256) void attn_kernel(const short* __restrict__ Q,
                                                   const short* __restrict__ K,
                                                   const short* __restrict__ V,
                                                   short* __restrict__ O) {
  constexpr int KST = 72;   // K tile LDS row stride (padded)
  constexpr int VST = 136;  // V^T tile LDS row stride (padded)
  constexpr int PST = 136;  // P tile LDS row stride (padded)
  __shared__ __align__(16) short Ks[128 * KST];
  __shared__ __align__(16) short Vs[64 * VST];
  __shared__ __align__(16) short Ps[128 * PST];

  const int tid = threadIdx.x;
  const int lane = tid & 63, wave = tid >> 6;
  const int l15 = lane & 15, quad = lane >> 4, lk8 = quad * 8;
  const int qt = blockIdx.x, bh = blockIdx.y;
  const int q0 = qt * 128;

  const short* Qb = Q + (size_t)bh * SEQ * DH;
  const short* Kb = K + (size_t)bh * SEQ * DH;
  const short* Vb = V + (size_t)bh * DH * SEQ;

  // Q fragments live in registers for the whole block
  s16x8 qf[2][2];
#pragma unroll
  for (int tq = 0; tq < 2; tq++)
#pragma unroll
    for (int ks = 0; ks < 2; ks++)
      qf[tq][ks] = *(const s16x8*)(Qb + (size_t)(q0 + wave * 32 + tq * 16 + l15) * DH + ks * 32 + lk8);

  f32x4 oacc[2][4];
#pragma unroll
  for (int i = 0; i < 2; i++)
#pragma unroll
    for (int j = 0; j < 4; j++) oacc[i][j] = (f32x4)0.f;
  float mrow[2][4], lrow[2][4];
#pragma unroll
  for (int i = 0; i < 2; i++)
#pragma unroll
    for (int j = 0; j < 4; j++) { mrow[i][j] = -3.0e38f; lrow[i][j] = 0.f; }

  constexpr float LOG2E = 1.44269504f;
  const float sc = 0.125f;  // 1/sqrt(64)

  for (int kt = 0; kt <= qt; kt++) {
    {  // stage K tile (contiguous rows -> padded LDS)
      const short* ksrc = Kb + (size_t)kt * 128 * DH;
#pragma unroll
      for (int i = 0; i < 4; i++) {
        int f = i * 256 + tid;
        int row = f >> 3, c = (f & 7) * 8;
        s16x8 v = *(const s16x8*)(ksrc + (size_t)row * DH + c);
        *(s16x8*)(Ks + row * KST + c) = v;
      }
      // stage V^T tile: rows are d (global stride SEQ), cols kk contiguous
      const short* vsrc = Vb + (size_t)kt * 128;
#pragma unroll
      for (int i = 0; i < 4; i++) {
        int f = i * 256 + tid;
        int d = f >> 4, c = (f & 15) * 8;
        s16x8 v = *(const s16x8*)(vsrc + (size_t)d * SEQ + c);
        *(s16x8*)(Vs + d * VST + c) = v;
      }
    }
    __syncthreads();

    // S = Q K^T : per wave 32 q-rows x 128 kk-cols
    f32x4 sacc[2][8];
#pragma unroll
    for (int i = 0; i < 2; i++)
#pragma unroll
      for (int j = 0; j < 8; j++) sacc[i][j] = (f32x4)0.f;
#pragma unroll
    for (int ks = 0; ks < 2; ks++) {
      s16x8 kf[8];
#pragma unroll
      for (int tn = 0; tn < 8; tn++)
        kf[tn] = *(const s16x8*)(Ks + (tn * 16 + l15) * KST + ks * 32 + lk8);
#pragma unroll
      for (int tq = 0; tq < 2; tq++)
#pragma unroll
        for (int tn = 0; tn < 8; tn++)
          sacc[tq][tn] = __builtin_amdgcn_mfma_f32_16x16x32_bf16(qf[tq][ks], kf[tn], sacc[tq][tn], 0, 0, 0);
    }

    const bool diag = (kt == qt);
#pragma unroll
    for (int tq = 0; tq < 2; tq++) {
#pragma unroll
      for (int r = 0; r < 4; r++) {
        const int qloc = wave * 32 + tq * 16 + quad * 4 + r;
        float sv[8];
        float mx = -3.0e38f;
#pragma unroll
        for (int tn = 0; tn < 8; tn++) {
          float s = sacc[tq][tn][r] * sc;
          if (diag && (tn * 16 + l15) > qloc) s = -3.0e38f;
          sv[tn] = s;
          mx = fmaxf(mx, s);
        }
#pragma unroll
        for (int off = 1; off < 16; off <<= 1) mx = fmaxf(mx, __shfl_xor(mx, off, 64));
        float mold = mrow[tq][r];
        float mnew = fmaxf(mold, mx);
        float alpha = exp2f((mold - mnew) * LOG2E);
        float rsum = 0.f;
        short* prow = Ps + qloc * PST;
#pragma unroll
        for (int tn = 0; tn < 8; tn++) {
          float p = exp2f((sv[tn] - mnew) * LOG2E);
          rsum += p;
          prow[tn * 16 + l15] = (short)f2bf(p);
        }
#pragma unroll
        for (int off = 1; off < 16; off <<= 1) rsum += __shfl_xor(rsum, off, 64);
        lrow[tq][r] = lrow[tq][r] * alpha + rsum;
        mrow[tq][r] = mnew;
#pragma unroll
        for (int td = 0; td < 4; td++) oacc[tq][td][r] *= alpha;
      }
    }

    // O += P * V  (Ps rows are intra-wave: lgkmcnt ordering suffices, no barrier)
#pragma unroll
    for (int ks = 0; ks < 4; ks++) {
      s16x8 pf[2], vf[4];
#pragma unroll
      for (int tq = 0; tq < 2; tq++)
        pf[tq] = *(const s16x8*)(Ps + (wave * 32 + tq * 16 + l15) * PST + ks * 32 + lk8);
#pragma unroll
      for (int td = 0; td < 4; td++)
        vf[td] = *(const s16x8*)(Vs + (td * 16 + l15) * VST + ks * 32 + lk8);
#pragma unroll
      for (int tq = 0; tq < 2; tq++)
#pragma unroll
        for (int td = 0; td < 4; td++)
          oacc[tq][td] = __builtin_amdgcn_mfma_f32_16x16x32_bf16(pf[tq], vf[td], oacc[tq][td], 0, 0, 0);
    }
    __syncthreads();
  }

  const int b = bh >> 4, h = bh & 15;
#pragma unroll
  for (int tq = 0; tq < 2; tq++) {
#pragma unroll
    for (int r = 0; r < 4; r++) {
      int q = q0 + wave * 32 + tq * 16 + quad * 4 + r;
      float inv = 1.f / lrow[tq][r];
#pragma unroll
      for (int td = 0; td < 4; td++) {
        int d = td * 16 + l15;
        O[((size_t)(b * SEQ + q)) * DM + h * DH + d] = (short)f2bf(oacc[tq][td][r] * inv);
      }
    }
  }
}

// ---------------- host launch ----------------
extern "C" void kernel_launch(void* const* d_in, const int* in_sizes, int n_in,
                              void* d_out, int out_size, void* d_ws, size_t ws_size,
                              hipStream_t stream) {
  const float* x  = (const float*)d_in[0];
  const float* wq = (const float*)d_in[1];
  const float* wk = (const float*)d_in[2];
  const float* wv = (const float*)d_in[3];
  const float* wo = (const float*)d_in[4];

  short* ws = (short*)d_ws;
  short* Xb  = ws;                   // [8192,1024] bf16, later reused as attention output O
  short* Wqb = Xb + (size_t)NROWS * DM;
  short* Wkb = Wqb + (size_t)DM * DM;
  short* Wvb = Wkb + (size_t)DM * DM;
  short* Wob = Wvb + (size_t)DM * DM;
  short* Qb  = Wob + (size_t)DM * DM;   // [B,NH,SEQ,DH]
  short* Kb  = Qb + (size_t)NROWS * DM;
  short* Vtb = Kb + (size_t)NROWS * DM; // [B,NH,DH,SEQ]
  short* Ob  = Xb;                      // alias: X no longer needed after QKV GEMMs

  // casts
  cast_bf16_kernel<<<(NROWS * DM / 8 + 255) / 256, 256, 0, stream>>>(x, Xb, NROWS * DM / 8);
  cast_bf16_kernel<<<(DM * DM / 8 + 255) / 256, 256, 0, stream>>>(wq, Wqb, DM * DM / 8);
  cast_bf16_kernel<<<(DM * DM / 8 + 255) / 256, 256, 0, stream>>>(wk, Wkb, DM * DM / 8);
  cast_bf16_kernel<<<(DM * DM / 8 + 255) / 256, 256, 0, stream>>>(wv, Wvb, DM * DM / 8);
  cast_bf16_kernel<<<(DM * DM / 8 + 255) / 256, 256, 0, stream>>>(wo, Wob, DM * DM / 8);

  dim3 gg(DM / 128, NROWS / 128);  // (8, 64)
  gemm_nt<1><<<gg, 256, 0, stream>>>(Xb, Wqb, Qb, NROWS, DM, DM);
  gemm_nt<1><<<gg, 256, 0, stream>>>(Xb, Wkb, Kb, NROWS, DM, DM);
  gemm_nt<3><<<gg, 256, 0, stream>>>(Xb, Wvb, Vtb, NROWS, DM, DM);

  attn_kernel<<<dim3(SEQ / 128, 4 * NH), 256, 0, stream>>>(Qb, Kb, Vtb, Ob);

  gemm_nt<2><<<gg, 256, 0, stream>>>(Ob, Wob, (float*)d_out, NROWS, DM, DM);
}

// Round 2
// 414.397 us; speedup vs baseline: 1.1765x; 1.1765x over previous
//
#include <hip/hip_runtime.h>
#include <stdint.h>
#include <stddef.h>

#define SEQ 2048
#define NH 16
#define DH 64
#define DM 1024
#define NROWS 8192  // B*T

typedef __attribute__((ext_vector_type(4))) float f32x4;
typedef __attribute__((ext_vector_type(16))) float f32x16;
typedef __attribute__((ext_vector_type(8))) short s16x8;
typedef __attribute__((ext_vector_type(4))) unsigned u32x4;

__device__ __forceinline__ unsigned short f2bf(float f) {
  unsigned int u = __builtin_bit_cast(unsigned int, f);
  u += 0x7fffu + ((u >> 16) & 1u);
  return (unsigned short)(u >> 16);
}

__device__ __forceinline__ float exp2fast(float x) {
#if __has_builtin(__builtin_amdgcn_exp2f)
  return __builtin_amdgcn_exp2f(x);
#else
  return exp2f(x);
#endif
}

__device__ __forceinline__ float rcpfast(float x) {
#if __has_builtin(__builtin_amdgcn_rcpf)
  return __builtin_amdgcn_rcpf(x);
#else
  return 1.0f / x;
#endif
}

// pack two f32 -> (bf16(lo) | bf16(hi)<<16), truncating round (P in (0,1], err < 2^-8 rel)
__device__ __forceinline__ unsigned pk2(float lo, float hi) {
  return __builtin_amdgcn_perm(__builtin_bit_cast(unsigned, hi),
                               __builtin_bit_cast(unsigned, lo), 0x07060302u);
}

__device__ __forceinline__ void async16(const void* g, void* l) {
  __builtin_amdgcn_global_load_lds(
      (const __attribute__((address_space(1))) unsigned int*)g,
      (__attribute__((address_space(3))) unsigned int*)l, 16, 0, 0);
}

// ---------------- fp32 -> bf16 cast (8 elems/thread) ----------------
__global__ __launch_bounds__(256) void cast_bf16_kernel(const float* __restrict__ src,
                                                        short* __restrict__ dst, int n8) {
  int i = blockIdx.x * 256 + threadIdx.x;
  if (i >= n8) return;
  const float4* s4 = (const float4*)src;
  float4 a = s4[2 * i], b = s4[2 * i + 1];
  s16x8 o;
  o[0] = (short)f2bf(a.x); o[1] = (short)f2bf(a.y);
  o[2] = (short)f2bf(a.z); o[3] = (short)f2bf(a.w);
  o[4] = (short)f2bf(b.x); o[5] = (short)f2bf(b.y);
  o[6] = (short)f2bf(b.z); o[7] = (short)f2bf(b.w);
  *(s16x8*)(dst + (size_t)8 * i) = o;
}

// ---------------- NT GEMM: C[m][n] = sum_k A[m][k] * B[n][k] ----------------
template <int MODE>
__global__ __launch_bounds__(256) void gemm_nt(const short* __restrict__ A,
                                               const short* __restrict__ B,
                                               void* __restrict__ C,
                                               int M, int N, int K) {
  __shared__ __align__(16) short As[128 * 32];
  __shared__ __align__(16) short Bs[128 * 32];
  const int tid = threadIdx.x;
  const int lane = tid & 63, wave = tid >> 6;
  const int l15 = lane & 15, quad = lane >> 4;
  const int lk8 = quad * 8;
  const int bm = blockIdx.y * 128, bn = blockIdx.x * 128;
  const int wm = (wave >> 1) * 64, wn = (wave & 1) * 64;

  const short* Ab = A + (size_t)bm * K;
  const short* Bb = B + (size_t)bn * K;

  f32x4 acc[4][4];
#pragma unroll
  for (int i = 0; i < 4; i++)
#pragma unroll
    for (int j = 0; j < 4; j++) acc[i][j] = (f32x4)0.f;

  const int srow = tid >> 2;
  const int scol = (tid & 3) * 8;

  for (int k0 = 0; k0 < K; k0 += 32) {
#pragma unroll
    for (int i = 0; i < 2; i++) {
      int row = i * 64 + srow;
      async16(Ab + (size_t)row * K + k0 + scol, As + ((size_t)(i * 256 + tid)) * 8);
      async16(Bb + (size_t)row * K + k0 + scol, Bs + ((size_t)(i * 256 + tid)) * 8);
    }
    __syncthreads();
    s16x8 af[4], bfr[4];
#pragma unroll
    for (int t = 0; t < 4; t++) af[t] = *(const s16x8*)(As + (wm + t * 16 + l15) * 32 + lk8);
#pragma unroll
    for (int t = 0; t < 4; t++) bfr[t] = *(const s16x8*)(Bs + (wn + t * 16 + l15) * 32 + lk8);
#pragma unroll
    for (int mt = 0; mt < 4; mt++)
#pragma unroll
      for (int nt = 0; nt < 4; nt++)
        acc[mt][nt] = __builtin_amdgcn_mfma_f32_16x16x32_bf16(af[mt], bfr[nt], acc[mt][nt], 0, 0, 0);
    __syncthreads();
  }

#pragma unroll
  for (int mt = 0; mt < 4; mt++) {
#pragma unroll
    for (int r = 0; r < 4; r++) {
      int m = bm + wm + mt * 16 + quad * 4 + r;
#pragma unroll
      for (int nt = 0; nt < 4; nt++) {
        int n = bn + wn + nt * 16 + l15;
        float v = acc[mt][nt][r];
        if constexpr (MODE == 2) {
          ((float*)C)[(size_t)m * N + n] = v;
        } else if constexpr (MODE == 0) {
          ((short*)C)[(size_t)m * N + n] = (short)f2bf(v);
        } else if constexpr (MODE == 1) {
          int b = m >> 11, t = m & (SEQ - 1);
          int hh = n >> 6, d = n & 63;
          ((short*)C)[((((size_t)b * NH + hh) * SEQ + t) << 6) + d] = (short)f2bf(v);
        } else {  // MODE 3: V transposed [B,NH,DH,SEQ]
          int b = m >> 11, t = m & (SEQ - 1);
          int hh = n >> 6, d = n & 63;
          ((short*)C)[(((size_t)b * NH + hh) * DH + d) * SEQ + t] = (short)f2bf(v);
        }
      }
    }
  }
}

// ---------------- causal flash attention, 32x32x16 MFMA, S^T scheme ----------------
// Q,K: [B,NH,SEQ,DH] bf16; V: [B,NH,DH,SEQ] bf16 (V^T); O: [B,SEQ,DM] bf16
// S^T = K*Q^T via mfma(A=K-frag, B=Q-frag): C/D col = q = lane&31, row = kk-map.
// P(C/D) -> PV A-operand needs only a lane^32 exchange (pack + 4 shfl_xor + selects).
__global__ __launch_bounds__(256, 3) void attn_kernel(const short* __restrict__ Q,
                                                      const short* __restrict__ K,
                                                      const short* __restrict__ V,
                                                      short* __restrict__ O) {
  __shared__ __align__(16) short Ks[128 * 64];  // XOR-swizzled 16B chunks, no pad
  __shared__ __align__(16) short Vs[64 * 128];  // XOR-swizzled 16B chunks, no pad

  const int tid = threadIdx.x;
  const int lane = tid & 63, wave = tid >> 6;
  const int l31 = lane & 31, h = lane >> 5;
  const int qt = (int)(gridDim.x - 1) - (int)blockIdx.x;  // heavy tiles dispatched first
  const int bh = blockIdx.y;
  const int q0 = qt * 128;

  const short* Qb = Q + (size_t)bh * SEQ * DH;
  const short* Kb = K + (size_t)bh * SEQ * DH;
  const short* Vb = V + (size_t)bh * DH * SEQ;

  // Q B-fragments (per mfma k-step ks): B[k=ks*16+h*8+j][n=q=l31]
  s16x8 qf[4];
#pragma unroll
  for (int ks = 0; ks < 4; ks++)
    qf[ks] = *(const s16x8*)(Qb + (size_t)(q0 + wave * 32 + l31) * DH + ks * 16 + h * 8);

  f32x16 oacc[2];
  oacc[0] = (f32x16)0.f;
  oacc[1] = (f32x16)0.f;
  float m_own = -3.0e38f, l_own = 0.f;
  const float C = 0.18033688011112042f;  // (1/sqrt(64)) * log2(e)

  for (int kt = 0; kt <= qt; kt++) {
    // ---- stage K tile (swizzle: phys chunk p in row kk holds logical chunk p^(kk&7)) ----
#pragma unroll
    for (int i = 0; i < 4; i++) {
      int f = i * 256 + tid;
      int kk = f >> 3, c8 = (f & 7) ^ (kk & 7);
      async16(Kb + ((size_t)(kt * 128 + kk)) * DH + c8 * 8, Ks + (size_t)f * 8);
    }
    // ---- stage V^T tile (phys chunk p in row d holds logical chunk p^(d&15)) ----
#pragma unroll
    for (int i = 0; i < 4; i++) {
      int f = i * 256 + tid;
      int d = f >> 4, c16 = (f & 15) ^ (d & 15);
      async16(Vb + (size_t)d * SEQ + kt * 128 + c16 * 8, Vs + (size_t)f * 8);
    }
    __syncthreads();

    // ---- S^T = K Q^T : 4 kk-tiles of 32x32, chained over 4 k-steps ----
    f32x16 sacc[4];
#pragma unroll
    for (int T = 0; T < 4; T++) sacc[T] = (f32x16)0.f;
#pragma unroll
    for (int ks = 0; ks < 4; ks++) {
#pragma unroll
      for (int T = 0; T < 4; T++) {
        s16x8 kf = *(const s16x8*)(Ks + (T * 32 + l31) * 64 + (((2 * ks + h) ^ (l31 & 7)) * 8));
        sacc[T] = __builtin_amdgcn_mfma_f32_32x32x16_bf16(kf, qf[ks], sacc[T], 0, 0, 0);
      }
    }

    // ---- causal mask (diagonal tile only): kk_local > q_local ----
    if (kt == qt) {
      int limit = wave * 32 + l31 - 4 * h;
#pragma unroll
      for (int T = 0; T < 4; T++)
#pragma unroll
        for (int r = 0; r < 16; r++) {
          int kkc = T * 32 + (r & 3) + 8 * (r >> 2);
          if (kkc > limit) sacc[T][r] = -3.0e38f;
        }
    }

    // ---- row max: in-lane tree over 64 + cross-half shfl ----
    float tm[4];
#pragma unroll
    for (int T = 0; T < 4; T++) {
      float a = fmaxf(fmaxf(sacc[T][0], sacc[T][1]), fmaxf(sacc[T][2], sacc[T][3]));
      float b = fmaxf(fmaxf(sacc[T][4], sacc[T][5]), fmaxf(sacc[T][6], sacc[T][7]));
      float c = fmaxf(fmaxf(sacc[T][8], sacc[T][9]), fmaxf(sacc[T][10], sacc[T][11]));
      float d = fmaxf(fmaxf(sacc[T][12], sacc[T][13]), fmaxf(sacc[T][14], sacc[T][15]));
      tm[T] = fmaxf(fmaxf(a, b), fmaxf(c, d));
    }
    float mx = fmaxf(fmaxf(tm[0], tm[1]), fmaxf(tm[2], tm[3]));
    mx = fmaxf(mx, __shfl_xor(mx, 32, 64));
    float mnew = fmaxf(m_own, mx);
    float mb = mnew * C;
    float alpha = exp2fast(m_own * C - mb);
    m_own = mnew;

    // ---- exp in place + row sum ----
    float ts[4];
#pragma unroll
    for (int T = 0; T < 4; T++) {
#pragma unroll
      for (int r = 0; r < 16; r++) sacc[T][r] = exp2fast(fmaf(sacc[T][r], C, -mb));
      float a = (sacc[T][0] + sacc[T][1]) + (sacc[T][2] + sacc[T][3]);
      float b = (sacc[T][4] + sacc[T][5]) + (sacc[T][6] + sacc[T][7]);
      float c = (sacc[T][8] + sacc[T][9]) + (sacc[T][10] + sacc[T][11]);
      float d = (sacc[T][12] + sacc[T][13]) + (sacc[T][14] + sacc[T][15]);
      ts[T] = (a + b) + (c + d);
    }
    float rsum = (ts[0] + ts[1]) + (ts[2] + ts[3]);
    rsum += __shfl_xor(rsum, 32, 64);
    l_own = l_own * alpha + rsum;

    // ---- pack to bf16 pairs, lane^32 exchange -> PV A-fragments ----
    s16x8 pf[8];
#pragma unroll
    for (int T = 0; T < 4; T++) {
      unsigned P0 = pk2(sacc[T][0], sacc[T][1]);
      unsigned P1 = pk2(sacc[T][2], sacc[T][3]);
      unsigned P2 = pk2(sacc[T][4], sacc[T][5]);
      unsigned P3 = pk2(sacc[T][6], sacc[T][7]);
      unsigned P4 = pk2(sacc[T][8], sacc[T][9]);
      unsigned P5 = pk2(sacc[T][10], sacc[T][11]);
      unsigned P6 = pk2(sacc[T][12], sacc[T][13]);
      unsigned P7 = pk2(sacc[T][14], sacc[T][15]);
      // h=0 lane needs partner's P0,P1,P4,P5; h=1 needs partner's P2,P3,P6,P7
      unsigned R0 = (unsigned)__shfl_xor((int)(h ? P0 : P2), 32, 64);
      unsigned R1 = (unsigned)__shfl_xor((int)(h ? P1 : P3), 32, 64);
      unsigned R2 = (unsigned)__shfl_xor((int)(h ? P4 : P6), 32, 64);
      unsigned R3 = (unsigned)__shfl_xor((int)(h ? P5 : P7), 32, 64);
      u32x4 lo, hi;
      lo[0] = h ? R0 : P0; lo[1] = h ? R1 : P1; lo[2] = h ? P2 : R0; lo[3] = h ? P3 : R1;
      hi[0] = h ? R2 : P4; hi[1] = h ? R3 : P5; hi[2] = h ? P6 : R2; hi[3] = h ? P7 : R3;
      pf[2 * T] = __builtin_bit_cast(s16x8, lo);
      pf[2 * T + 1] = __builtin_bit_cast(s16x8, hi);
    }

    // ---- rescale O by alpha (broadcast to O-row layout) ----
#pragma unroll
    for (int r = 0; r < 16; r++) {
      float av = __shfl(alpha, (r & 3) + 8 * (r >> 2) + 4 * h, 64);
      oacc[0][r] *= av;
      oacc[1][r] *= av;
    }

    // ---- O += P V : B[k=kc*16+h*8+j][n=d] from swizzled Vs ----
#pragma unroll
    for (int kc = 0; kc < 8; kc++) {
#pragma unroll
      for (int td = 0; td < 2; td++) {
        s16x8 vf = *(const s16x8*)(Vs + (td * 32 + l31) * 128 + (((2 * kc + h) ^ (l31 & 15)) * 8));
        oacc[td] = __builtin_amdgcn_mfma_f32_32x32x16_bf16(pf[kc], vf, oacc[td], 0, 0, 0);
      }
    }
    __syncthreads();
  }

  // ---- epilogue: normalize by 1/l, write O[B,SEQ,DM] bf16 ----
  const int b = bh >> 4, head = bh & 15;
  float inv = rcpfast(l_own);
#pragma unroll
  for (int r = 0; r < 16; r++) {
    int rmap = (r & 3) + 8 * (r >> 2) + 4 * h;
    float iv = __shfl(inv, rmap, 64);
    int q = q0 + wave * 32 + rmap;
#pragma unroll
    for (int td = 0; td < 2; td++) {
      O[((size_t)(b * SEQ + q)) * DM + head * DH + td * 32 + l31] = (short)f2bf(oacc[td][r] * iv);
    }
  }
}

// ---------------- host launch ----------------
extern "C" void kernel_launch(void* const* d_in, const int* in_sizes, int n_in,
                              void* d_out, int out_size, void* d_ws, size_t ws_size,
                              hipStream_t stream) {
  const float* x  = (const float*)d_in[0];
  const float* wq = (const float*)d_in[1];
  const float* wk = (const float*)d_in[2];
  const float* wv = (const float*)d_in[3];
  const float* wo = (const float*)d_in[4];

  short* ws = (short*)d_ws;
  short* Xb  = ws;
  short* Wqb = Xb + (size_t)NROWS * DM;
  short* Wkb = Wqb + (size_t)DM * DM;
  short* Wvb = Wkb + (size_t)DM * DM;
  short* Wob = Wvb + (size_t)DM * DM;
  short* Qb  = Wob + (size_t)DM * DM;   // [B,NH,SEQ,DH]
  short* Kb  = Qb + (size_t)NROWS * DM;
  short* Vtb = Kb + (size_t)NROWS * DM; // [B,NH,DH,SEQ]
  short* Ob  = Xb;                      // alias: X dead after QKV GEMMs

  cast_bf16_kernel<<<(NROWS * DM / 8 + 255) / 256, 256, 0, stream>>>(x, Xb, NROWS * DM / 8);
  cast_bf16_kernel<<<(DM * DM / 8 + 255) / 256, 256, 0, stream>>>(wq, Wqb, DM * DM / 8);
  cast_bf16_kernel<<<(DM * DM / 8 + 255) / 256, 256, 0, stream>>>(wk, Wkb, DM * DM / 8);
  cast_bf16_kernel<<<(DM * DM / 8 + 255) / 256, 256, 0, stream>>>(wv, Wvb, DM * DM / 8);
  cast_bf16_kernel<<<(DM * DM / 8 + 255) / 256, 256, 0, stream>>>(wo, Wob, DM * DM / 8);

  dim3 gg(DM / 128, NROWS / 128);  // (8, 64)
  gemm_nt<1><<<gg, 256, 0, stream>>>(Xb, Wqb, Qb, NROWS, DM, DM);
  gemm_nt<1><<<gg, 256, 0, stream>>>(Xb, Wkb, Kb, NROWS, DM, DM);
  gemm_nt<3><<<gg, 256, 0, stream>>>(Xb, Wvb, Vtb, NROWS, DM, DM);

  attn_kernel<<<dim3(SEQ / 128, 4 * NH), 256, 0, stream>>>(Qb, Kb, Vtb, Ob);

  gemm_nt<2><<<gg, 256, 0, stream>>>(Ob, Wob, (float*)d_out, NROWS, DM, DM);
}

// Round 3
// 302.382 us; speedup vs baseline: 1.6124x; 1.3704x over previous
//
#include <hip/hip_runtime.h>
#include <stdint.h>
#include <stddef.h>

#define SEQ 2048
#define NH 16
#define DH 64
#define DM 1024
#define NROWS 8192  // B*T

typedef __attribute__((ext_vector_type(4))) float f32x4;
typedef __attribute__((ext_vector_type(16))) float f32x16;
typedef __attribute__((ext_vector_type(8))) short s16x8;
typedef __attribute__((ext_vector_type(4))) unsigned u32x4;

__device__ __forceinline__ unsigned short f2bf(float f) {
  unsigned int u = __builtin_bit_cast(unsigned int, f);
  u += 0x7fffu + ((u >> 16) & 1u);
  return (unsigned short)(u >> 16);
}

__device__ __forceinline__ float exp2fast(float x) {
#if __has_builtin(__builtin_amdgcn_exp2f)
  return __builtin_amdgcn_exp2f(x);
#else
  return exp2f(x);
#endif
}

__device__ __forceinline__ float rcpfast(float x) {
#if __has_builtin(__builtin_amdgcn_rcpf)
  return __builtin_amdgcn_rcpf(x);
#else
  return 1.0f / x;
#endif
}

// pack two f32 -> (bf16(lo) | bf16(hi)<<16), truncating (P in (0,1], rel err < 2^-8)
__device__ __forceinline__ unsigned pk2(float lo, float hi) {
  return __builtin_amdgcn_perm(__builtin_bit_cast(unsigned, hi),
                               __builtin_bit_cast(unsigned, lo), 0x07060302u);
}

__device__ __forceinline__ void async16(const void* g, void* l) {
  __builtin_amdgcn_global_load_lds(
      (const __attribute__((address_space(1))) unsigned int*)g,
      (__attribute__((address_space(3))) unsigned int*)l, 16, 0, 0);
}

// ---------------- fp32 -> bf16 cast (8 elems/thread) ----------------
__global__ __launch_bounds__(256) void cast_bf16_kernel(const float* __restrict__ src,
                                                        short* __restrict__ dst, int n8) {
  int i = blockIdx.x * 256 + threadIdx.x;
  if (i >= n8) return;
  const float4* s4 = (const float4*)src;
  float4 a = s4[2 * i], b = s4[2 * i + 1];
  s16x8 o;
  o[0] = (short)f2bf(a.x); o[1] = (short)f2bf(a.y);
  o[2] = (short)f2bf(a.z); o[3] = (short)f2bf(a.w);
  o[4] = (short)f2bf(b.x); o[5] = (short)f2bf(b.y);
  o[6] = (short)f2bf(b.z); o[7] = (short)f2bf(b.w);
  *(s16x8*)(dst + (size_t)8 * i) = o;
}

// ---------------- NT GEMM: C[m][n] = sum_k A[m][k] * B[n][k] ----------------
// MODE 1: C bf16 scatter [B,NH,SEQ,DH] (Q/K). MODE 2: C fp32 row-major.
// MODE 3: C bf16 scatter [B,NH,DH,SEQ] (V^T) -- MFMA operands swapped so the
//         token dim lands in lanes => coalesced 32B runs along SEQ.
template <int MODE>
__global__ __launch_bounds__(256) void gemm_nt(const short* __restrict__ A,
                                               const short* __restrict__ B,
                                               void* __restrict__ C,
                                               int M, int N, int K) {
  __shared__ __align__(16) short As[128 * 32];
  __shared__ __align__(16) short Bs[128 * 32];
  const int tid = threadIdx.x;
  const int lane = tid & 63, wave = tid >> 6;
  const int l15 = lane & 15, quad = lane >> 4;
  const int lk8 = quad * 8;
  const int bm = blockIdx.y * 128, bn = blockIdx.x * 128;
  const int wm = (wave >> 1) * 64, wn = (wave & 1) * 64;

  const short* Ab = A + (size_t)bm * K;
  const short* Bb = B + (size_t)bn * K;

  f32x4 acc[4][4];
#pragma unroll
  for (int i = 0; i < 4; i++)
#pragma unroll
    for (int j = 0; j < 4; j++) acc[i][j] = (f32x4)0.f;

  const int srow = tid >> 2;
  const int scol = (tid & 3) * 8;

  for (int k0 = 0; k0 < K; k0 += 32) {
#pragma unroll
    for (int i = 0; i < 2; i++) {
      int row = i * 64 + srow;
      async16(Ab + (size_t)row * K + k0 + scol, As + ((size_t)(i * 256 + tid)) * 8);
      async16(Bb + (size_t)row * K + k0 + scol, Bs + ((size_t)(i * 256 + tid)) * 8);
    }
    __syncthreads();
    s16x8 af[4], bfr[4];
#pragma unroll
    for (int t = 0; t < 4; t++) af[t] = *(const s16x8*)(As + (wm + t * 16 + l15) * 32 + lk8);
#pragma unroll
    for (int t = 0; t < 4; t++) bfr[t] = *(const s16x8*)(Bs + (wn + t * 16 + l15) * 32 + lk8);
#pragma unroll
    for (int mt = 0; mt < 4; mt++)
#pragma unroll
      for (int nt = 0; nt < 4; nt++) {
        if constexpr (MODE == 3)
          acc[mt][nt] = __builtin_amdgcn_mfma_f32_16x16x32_bf16(bfr[nt], af[mt], acc[mt][nt], 0, 0, 0);
        else
          acc[mt][nt] = __builtin_amdgcn_mfma_f32_16x16x32_bf16(af[mt], bfr[nt], acc[mt][nt], 0, 0, 0);
      }
    __syncthreads();
  }

#pragma unroll
  for (int mt = 0; mt < 4; mt++) {
#pragma unroll
    for (int r = 0; r < 4; r++) {
#pragma unroll
      for (int nt = 0; nt < 4; nt++) {
        float v = acc[mt][nt][r];
        if constexpr (MODE == 3) {
          // D transposed: col(lane&15)=m token, row(quad*4+r)=n
          int n = bn + wn + nt * 16 + quad * 4 + r;  // d-dim
          int m = bm + wm + mt * 16 + l15;           // token
          int b = m >> 11, t = m & (SEQ - 1);
          int hh = n >> 6, d = n & 63;
          ((short*)C)[(((size_t)b * NH + hh) * DH + d) * SEQ + t] = (short)f2bf(v);
        } else {
          int m = bm + wm + mt * 16 + quad * 4 + r;
          int n = bn + wn + nt * 16 + l15;
          if constexpr (MODE == 2) {
            ((float*)C)[(size_t)m * N + n] = v;
          } else {  // MODE 1
            int b = m >> 11, t = m & (SEQ - 1);
            int hh = n >> 6, d = n & 63;
            ((short*)C)[((((size_t)b * NH + hh) * SEQ + t) << 6) + d] = (short)f2bf(v);
          }
        }
      }
    }
  }
}

// ---------------- causal flash attention, 32x32x16 MFMA, O^T scheme ----------------
// Q,K: [B,NH,SEQ,DH] bf16; V: [B,NH,DH,SEQ] bf16 (V^T); O: [B,SEQ,DM] bf16
// S^T = K Q^T (q in lanes) -> softmax state lane-local -> O^T = V^T P^T (q in lanes,
// d in registers) -> alpha/l rescale lane-local, no broadcasts. Double-buffered LDS
// staging with ONE barrier per K-tile. Block schedule: id&7 -> XCD, 8 heads/XCD so
// each head's 512KB K/V stays in its XCD L2 across all 16 q-tile blocks.
__global__ __launch_bounds__(256, 2) void attn_kernel(const short* __restrict__ Q,
                                                      const short* __restrict__ K,
                                                      const short* __restrict__ V,
                                                      short* __restrict__ O) {
  __shared__ __align__(16) short Smem[2 * 16384];  // 2 x (K 8192 + V 8192 shorts) = 64KB

  const int tid = threadIdx.x;
  const int lane = tid & 63, wave = tid >> 6;
  const int l31 = lane & 31, h = lane >> 5;

  // schedule: c = XCD slot, s>>4 = head-within-XCD, s&15 = q-tile (heavy first)
  const int c = blockIdx.x & 7, s = blockIdx.x >> 3;
  const int bh = c * 8 + (s >> 4);
  const int qt = 15 - (s & 15);
  const int q0 = qt * 128;

  const short* Qb = Q + (size_t)bh * SEQ * DH;
  const short* Kb = K + (size_t)bh * SEQ * DH;
  const short* Vb = V + (size_t)bh * DH * SEQ;

  auto stage = [&](int ktile, int bufsel) {
    short* base = Smem + bufsel * 16384;
    const short* ksrc = Kb + (size_t)ktile * 128 * DH;
#pragma unroll
    for (int i = 0; i < 4; i++) {
      int f = i * 256 + tid;
      int kk = f >> 3, c8 = (f & 7) ^ (kk & 7);
      async16(ksrc + (size_t)kk * DH + c8 * 8, base + (size_t)f * 8);
    }
    const short* vsrc = Vb + (size_t)ktile * 128;
#pragma unroll
    for (int i = 0; i < 4; i++) {
      int f = i * 256 + tid;
      int d = f >> 4, c16 = (f & 15) ^ (d & 15);
      async16(vsrc + (size_t)d * SEQ + c16 * 8, base + 8192 + (size_t)f * 8);
    }
  };

  // Q B-fragments: B[k=ks*16+h*8+j][n=q=l31]
  s16x8 qf[4];
#pragma unroll
  for (int ks = 0; ks < 4; ks++)
    qf[ks] = *(const s16x8*)(Qb + (size_t)(q0 + wave * 32 + l31) * DH + ks * 16 + h * 8);

  f32x16 oacc[2];
  oacc[0] = (f32x16)0.f;
  oacc[1] = (f32x16)0.f;
  float m_own = -3.0e38f, l_own = 0.f;
  const float C = 0.18033688011112042f;  // (1/sqrt(64)) * log2(e)

  stage(0, 0);

  for (int kt = 0; kt <= qt; kt++) {
    const int cur = kt & 1;
    __syncthreads();  // drains vmcnt: buf[cur] ready (its loads aged one compute phase)
    if (kt < qt) stage(kt + 1, cur ^ 1);
    const short* Ks = Smem + cur * 16384;
    const short* Vs = Ks + 8192;

    // ---- S^T = K Q^T : 4 kk-tiles of 32x32 ----
    f32x16 sacc[4];
#pragma unroll
    for (int T = 0; T < 4; T++) sacc[T] = (f32x16)0.f;
#pragma unroll
    for (int ks = 0; ks < 4; ks++) {
#pragma unroll
      for (int T = 0; T < 4; T++) {
        s16x8 kf = *(const s16x8*)(Ks + (T * 32 + l31) * 64 + (((2 * ks + h) ^ (l31 & 7)) * 8));
        sacc[T] = __builtin_amdgcn_mfma_f32_32x32x16_bf16(kf, qf[ks], sacc[T], 0, 0, 0);
      }
    }

    // ---- causal mask (diagonal tile only) ----
    if (kt == qt) {
      int limit = wave * 32 + l31 - 4 * h;
#pragma unroll
      for (int T = 0; T < 4; T++)
#pragma unroll
        for (int r = 0; r < 16; r++) {
          int kkc = T * 32 + (r & 3) + 8 * (r >> 2);
          if (kkc > limit) sacc[T][r] = -3.0e38f;
        }
    }

    // ---- row max (q = l31 lane-local; combine halves) ----
    float tm[4];
#pragma unroll
    for (int T = 0; T < 4; T++) {
      float a = fmaxf(fmaxf(sacc[T][0], sacc[T][1]), fmaxf(sacc[T][2], sacc[T][3]));
      float b = fmaxf(fmaxf(sacc[T][4], sacc[T][5]), fmaxf(sacc[T][6], sacc[T][7]));
      float cc = fmaxf(fmaxf(sacc[T][8], sacc[T][9]), fmaxf(sacc[T][10], sacc[T][11]));
      float d = fmaxf(fmaxf(sacc[T][12], sacc[T][13]), fmaxf(sacc[T][14], sacc[T][15]));
      tm[T] = fmaxf(fmaxf(a, b), fmaxf(cc, d));
    }
    float mx = fmaxf(fmaxf(tm[0], tm[1]), fmaxf(tm[2], tm[3]));
    mx = fmaxf(mx, __shfl_xor(mx, 32, 64));
    float mnew = fmaxf(m_own, mx);
    float mb = mnew * C;
    float alpha = exp2fast(m_own * C - mb);
    m_own = mnew;

    // ---- exp in place + row sum ----
    float ts[4];
#pragma unroll
    for (int T = 0; T < 4; T++) {
#pragma unroll
      for (int r = 0; r < 16; r++) sacc[T][r] = exp2fast(fmaf(sacc[T][r], C, -mb));
      float a = (sacc[T][0] + sacc[T][1]) + (sacc[T][2] + sacc[T][3]);
      float b = (sacc[T][4] + sacc[T][5]) + (sacc[T][6] + sacc[T][7]);
      float cc = (sacc[T][8] + sacc[T][9]) + (sacc[T][10] + sacc[T][11]);
      float d = (sacc[T][12] + sacc[T][13]) + (sacc[T][14] + sacc[T][15]);
      ts[T] = (a + b) + (cc + d);
    }
    float rsum = (ts[0] + ts[1]) + (ts[2] + ts[3]);
    rsum += __shfl_xor(rsum, 32, 64);
    l_own = l_own * alpha + rsum;

    // ---- pack to bf16, lane^32 exchange -> P^T B-fragments ----
    s16x8 pf[8];
#pragma unroll
    for (int T = 0; T < 4; T++) {
      unsigned P0 = pk2(sacc[T][0], sacc[T][1]);
      unsigned P1 = pk2(sacc[T][2], sacc[T][3]);
      unsigned P2 = pk2(sacc[T][4], sacc[T][5]);
      unsigned P3 = pk2(sacc[T][6], sacc[T][7]);
      unsigned P4 = pk2(sacc[T][8], sacc[T][9]);
      unsigned P5 = pk2(sacc[T][10], sacc[T][11]);
      unsigned P6 = pk2(sacc[T][12], sacc[T][13]);
      unsigned P7 = pk2(sacc[T][14], sacc[T][15]);
      unsigned R0 = (unsigned)__shfl_xor((int)(h ? P0 : P2), 32, 64);
      unsigned R1 = (unsigned)__shfl_xor((int)(h ? P1 : P3), 32, 64);
      unsigned R2 = (unsigned)__shfl_xor((int)(h ? P4 : P6), 32, 64);
      unsigned R3 = (unsigned)__shfl_xor((int)(h ? P5 : P7), 32, 64);
      u32x4 lo, hi;
      lo[0] = h ? R0 : P0; lo[1] = h ? R1 : P1; lo[2] = h ? P2 : R0; lo[3] = h ? P3 : R1;
      hi[0] = h ? R2 : P4; hi[1] = h ? R3 : P5; hi[2] = h ? P6 : R2; hi[3] = h ? P7 : R3;
      pf[2 * T] = __builtin_bit_cast(s16x8, lo);
      pf[2 * T + 1] = __builtin_bit_cast(s16x8, hi);
    }

    // ---- rescale O^T by alpha: lane-local (q = l31) ----
#pragma unroll
    for (int r = 0; r < 16; r++) {
      oacc[0][r] *= alpha;
      oacc[1][r] *= alpha;
    }

    // ---- O^T += V^T P^T : A = V^T frag, B = P^T frag ----
#pragma unroll
    for (int kc = 0; kc < 8; kc++) {
#pragma unroll
      for (int td = 0; td < 2; td++) {
        s16x8 vf = *(const s16x8*)(Vs + (td * 32 + l31) * 128 + (((2 * kc + h) ^ (l31 & 15)) * 8));
        oacc[td] = __builtin_amdgcn_mfma_f32_32x32x16_bf16(vf, pf[kc], oacc[td], 0, 0, 0);
      }
    }
  }

  // ---- epilogue: lane-local 1/l, transpose O^T -> O via padded LDS, coalesced store ----
  __syncthreads();  // all waves done reading K/V buffers
  const int b = bh >> 4, head = bh & 15;
  float inv = rcpfast(l_own);
  const int g = lane >> 3, d4 = (lane & 7) * 4;
#pragma unroll
  for (int td = 0; td < 2; td++) {
    float* tb = (float*)Smem + (size_t)(wave * 2 + td) * 1056;  // 32 d-rows x 33 (pad)
#pragma unroll
    for (int r = 0; r < 16; r++) {
      int d_loc = (r & 3) + 8 * (r >> 2) + 4 * h;
      tb[d_loc * 33 + l31] = oacc[td][r] * inv;
    }
    // same-wave DS ops are in-order: reads below see all lanes' writes above
#pragma unroll
    for (int j = 0; j < 4; j++) {
      int qq = j * 8 + g;
      float x0 = tb[(d4 + 0) * 33 + qq];
      float x1 = tb[(d4 + 1) * 33 + qq];
      float x2 = tb[(d4 + 2) * 33 + qq];
      float x3 = tb[(d4 + 3) * 33 + qq];
      uint2 pkd;
      pkd.x = (unsigned)f2bf(x0) | ((unsigned)f2bf(x1) << 16);
      pkd.y = (unsigned)f2bf(x2) | ((unsigned)f2bf(x3) << 16);
      int q = q0 + wave * 32 + qq;
      *(uint2*)(O + ((size_t)(b * SEQ + q)) * DM + head * DH + td * 32 + d4) = pkd;
    }
  }
}

// ---------------- host launch ----------------
extern "C" void kernel_launch(void* const* d_in, const int* in_sizes, int n_in,
                              void* d_out, int out_size, void* d_ws, size_t ws_size,
                              hipStream_t stream) {
  const float* x  = (const float*)d_in[0];
  const float* wq = (const float*)d_in[1];
  const float* wk = (const float*)d_in[2];
  const float* wv = (const float*)d_in[3];
  const float* wo = (const float*)d_in[4];

  short* ws = (short*)d_ws;
  short* Xb  = ws;
  short* Wqb = Xb + (size_t)NROWS * DM;
  short* Wkb = Wqb + (size_t)DM * DM;
  short* Wvb = Wkb + (size_t)DM * DM;
  short* Wob = Wvb + (size_t)DM * DM;
  short* Qb  = Wob + (size_t)DM * DM;   // [B,NH,SEQ,DH]
  short* Kb  = Qb + (size_t)NROWS * DM;
  short* Vtb = Kb + (size_t)NROWS * DM; // [B,NH,DH,SEQ]
  short* Ob  = Xb;                      // alias: X dead after QKV GEMMs

  cast_bf16_kernel<<<(NROWS * DM / 8 + 255) / 256, 256, 0, stream>>>(x, Xb, NROWS * DM / 8);
  cast_bf16_kernel<<<(DM * DM / 8 + 255) / 256, 256, 0, stream>>>(wq, Wqb, DM * DM / 8);
  cast_bf16_kernel<<<(DM * DM / 8 + 255) / 256, 256, 0, stream>>>(wk, Wkb, DM * DM / 8);
  cast_bf16_kernel<<<(DM * DM / 8 + 255) / 256, 256, 0, stream>>>(wv, Wvb, DM * DM / 8);
  cast_bf16_kernel<<<(DM * DM / 8 + 255) / 256, 256, 0, stream>>>(wo, Wob, DM * DM / 8);

  dim3 gg(DM / 128, NROWS / 128);  // (8, 64)
  gemm_nt<1><<<gg, 256, 0, stream>>>(Xb, Wqb, Qb, NROWS, DM, DM);
  gemm_nt<1><<<gg, 256, 0, stream>>>(Xb, Wkb, Kb, NROWS, DM, DM);
  gemm_nt<3><<<gg, 256, 0, stream>>>(Xb, Wvb, Vtb, NROWS, DM, DM);

  attn_kernel<<<1024, 256, 0, stream>>>(Qb, Kb, Vtb, Ob);

  gemm_nt<2><<<gg, 256, 0, stream>>>(Ob, Wob, (float*)d_out, NROWS, DM, DM);
}